// Round 5
// baseline (131.267 us; speedup 1.0000x reference)
//
#include <hip/hip_runtime.h>
#include <stdint.h>

#define BB 64
#define LL 512
#define DD 300
#define CC 128
#define NP 64  // partials per batch (16 token-chunks x 4 token-groups)

// ws layout (floats):
//   Gpart : [64][64][3][300] = 3,686,400  (per-(chunk,token-group) partials)
//   Gred  : [64][900]        =    57,600  (float4 view: [64][225])
//   W2    : [128][900]       =   115,200  (fused sim.fc weights)
//   bias2 : [128]
#define OFF_GRED  (BB * NP * 3 * DD)
#define OFF_W2    (OFF_GRED + BB * 3 * DD)
#define OFF_BIAS2 (OFF_W2 + CC * 3 * DD)

// ---------------------------------------------------------------------------
// Kernel 1: gather + head-weight precompute, one grid of 320-thread blocks.
// Blocks 0..1023: gather for (b = blk>>4, tc = blk&15), 32 tokens.
//   300 active threads = 4 token-groups (tg) x 75 float4-slots (d4).
//   Thread (tg,d4): v[i] = embed[sx[tg*8+i]][4*d4..4*d4+3] (float4, 8-deep
//   batch = 128 B in flight vs 64 B for the old float2 version; 2400 loads
//   per block vs 4800), acc_kk += su[kk][token]*v.
//   Writes partial p = tc*4+tg of Gpart[b].
// Blocks 1024..1407: W2 precompute (1920 waves = 384 blocks x 5 waves).
// Blocks 1408..1433: bias2 (130 waves, c<128 guarded).
// ---------------------------------------------------------------------------
__global__ __launch_bounds__(320) void k_gather(
    const int* __restrict__ x, const float* __restrict__ embed,
    const float* __restrict__ conv_w, const float* __restrict__ conv_b,
    const float* __restrict__ w3, const float* __restrict__ b3,
    const float* __restrict__ w4, const float* __restrict__ b4,
    const float* __restrict__ w5, const float* __restrict__ b5,
    const float* __restrict__ fcw, const float* __restrict__ fcb,
    float* __restrict__ Gpart, float* __restrict__ W2,
    float* __restrict__ bias2) {
  const int blk = blockIdx.x;
  const int tid = threadIdx.x;

  if (blk < 1024) {  // ---------------- gather ----------------
    const int b = blk >> 4;
    const int tc = blk & 15;

    __shared__ int sx[32];
    __shared__ float su[3][32];

    if (tid < 32) {
      const int t = tc * 32 + tid;
      sx[tid] = x[b * LL + t];
      const float* ws[3] = {w3, w4, w5};
#pragma unroll
      for (int kk = 0; kk < 3; ++kk) {
        const int k = kk + 3;
        int lo = t - k + 1; if (lo < 0) lo = 0;
        int hi = t; const int lim = LL - k - 1; if (hi > lim) hi = lim;
        float s = 0.f;
        for (int l = lo; l <= hi; ++l) s += ws[kk][l];
        su[kk][tid] = s;
      }
    }
    __syncthreads();

    if (tid < 300) {
      const int tg = tid / 75;        // token-group 0..3 (8 tokens each)
      const int d4 = tid - tg * 75;   // float4 slot 0..74
      const int i0 = tg * 8;

      float4 v[8];
#pragma unroll
      for (int i = 0; i < 8; ++i) {
        const float4* rp = (const float4*)(embed + (size_t)sx[i0 + i] * DD);
        v[i] = rp[d4];
      }

      float4 a0 = {0.f, 0.f, 0.f, 0.f};
      float4 a1 = {0.f, 0.f, 0.f, 0.f};
      float4 a2 = {0.f, 0.f, 0.f, 0.f};
#pragma unroll
      for (int i = 0; i < 8; ++i) {
        const int j = i0 + i;
        const float w0 = su[0][j], w1 = su[1][j], w2 = su[2][j];
        a0.x += w0 * v[i].x; a0.y += w0 * v[i].y;
        a0.z += w0 * v[i].z; a0.w += w0 * v[i].w;
        a1.x += w1 * v[i].x; a1.y += w1 * v[i].y;
        a1.z += w1 * v[i].z; a1.w += w1 * v[i].w;
        a2.x += w2 * v[i].x; a2.y += w2 * v[i].y;
        a2.z += w2 * v[i].z; a2.w += w2 * v[i].w;
      }

      const int p = tc * 4 + tg;  // 0..63
      float* Gp = Gpart + (size_t)(b * NP + p) * (3 * DD);
      ((float4*)(Gp + 0 * DD))[d4] = a0;
      ((float4*)(Gp + 1 * DD))[d4] = a1;
      ((float4*)(Gp + 2 * DD))[d4] = a2;
    }
  } else if (blk < 1408) {  // ---------------- W2 precompute ----------------
    const int w = (blk - 1024) * 5 + (tid >> 6);  // 0..1919
    const int lane = tid & 63;
    const int c = w / 15;
    const int rem = w - c * 15;
    const int kk = rem / 5;
    const int chunk = rem - kk * 5;
    const int d = chunk * 64 + lane;
    if (d < DD) {
      const float* fr = fcw + c * (3 * CC) + kk * CC;  // 128 wave-uniform
      float acc0 = 0.f, acc1 = 0.f;
#pragma unroll 4
      for (int cp = 0; cp < CC; cp += 2) {
        acc0 += fr[cp] * conv_w[cp * DD + d];
        acc1 += fr[cp + 1] * conv_w[(cp + 1) * DD + d];
      }
      W2[c * (3 * DD) + kk * DD + d] = acc0 + acc1;
    }
  } else {  // ---------------- bias2 ----------------
    const int wid = tid >> 6;
    const int lane = tid & 63;
    const int c = (blk - 1408) * 5 + wid;  // 0..129, guard below
    if (c < CC) {
      float sk[3];
      const float* ws[3] = {w3, w4, w5};
#pragma unroll
      for (int kk = 0; kk < 3; ++kk) {
        const int len = LL - (kk + 3);
        float s = 0.f;
        for (int l = lane; l < len; l += 64) s += ws[kk][l];
#pragma unroll
        for (int off = 32; off >= 1; off >>= 1) s += __shfl_down(s, off, 64);
        sk[kk] = __shfl(s, 0, 64);
      }
      const float bkv[3] = {b3[0], b4[0], b5[0]};
      float acc = 0.f;
#pragma unroll
      for (int s6 = 0; s6 < 6; ++s6) {
        const int j = s6 * 64 + lane;
        const int kk = j >> 7;
        const int cp = j & 127;
        acc += fcw[c * (3 * CC) + j] * (conv_b[cp] * sk[kk] + bkv[kk]);
      }
#pragma unroll
      for (int off = 32; off >= 1; off >>= 1) acc += __shfl_down(acc, off, 64);
      if (lane == 0) bias2[c] = acc + fcb[c];
    }
  }
}

// ---------------------------------------------------------------------------
// Kernel 2: Gpart -> Gred reduction. 900 blocks x 256 threads; 16 threads
// per float4 output (14,400 outputs), each sums 4 of the 64 partials
// (4-deep float4 load batch), then 4-step shuffle.
// ---------------------------------------------------------------------------
__global__ __launch_bounds__(256) void k_reduce(
    const float* __restrict__ Gpart, float* __restrict__ Gred) {
  const int gid = blockIdx.x * 256 + threadIdx.x;  // < 230400
  const int o = gid >> 4;   // float4 output id, < 14400
  const int r = gid & 15;   // partial-quad group 0..15
  const int b = o / 225;
  const int q = o - b * 225;
  const float4* gp =
      (const float4*)Gpart + ((size_t)b * NP + r * 4) * 225 + q;
  const float4 v0 = gp[0];
  const float4 v1 = gp[225];
  const float4 v2 = gp[450];
  const float4 v3 = gp[675];
  float4 s;
  s.x = (v0.x + v1.x) + (v2.x + v3.x);
  s.y = (v0.y + v1.y) + (v2.y + v3.y);
  s.z = (v0.z + v1.z) + (v2.z + v3.z);
  s.w = (v0.w + v1.w) + (v2.w + v3.w);
#pragma unroll
  for (int off = 1; off <= 8; off <<= 1) {
    s.x += __shfl_down(s.x, off, 64);
    s.y += __shfl_down(s.y, off, 64);
    s.z += __shfl_down(s.z, off, 64);
    s.w += __shfl_down(s.w, off, 64);
  }
  if (r == 0) ((float4*)Gred)[o] = s;
}

// ---------------------------------------------------------------------------
// Kernel 3: head GEMV, 1024 blocks x 256 threads. Wave wg -> channel pair
// (c0,c0+1) of batch b: out[b,c] = <W2[c,:], Gred[b,:]> + bias2[c].
// ---------------------------------------------------------------------------
__global__ __launch_bounds__(256) void k_out(
    const float* __restrict__ Gred, const float* __restrict__ W2,
    const float* __restrict__ bias2, float* __restrict__ out) {
  const int wg = blockIdx.x * 4 + (threadIdx.x >> 6);  // 0..4095
  const int lane = threadIdx.x & 63;
  const int b = wg >> 6;        // 0..63
  const int c0 = (wg & 63) * 2; // channel pair

  const float2* gr = (const float2*)(Gred + b * (3 * DD));    // 450 float2
  const float2* wr0 = (const float2*)(W2 + c0 * (3 * DD));
  const float2* wr1 = (const float2*)(W2 + (c0 + 1) * (3 * DD));
  float a0 = 0.f, a1 = 0.f;
#pragma unroll
  for (int s = 0; s < 7; ++s) {
    const float2 g = gr[s * 64 + lane];
    const float2 va = wr0[s * 64 + lane];
    const float2 vb = wr1[s * 64 + lane];
    a0 += va.x * g.x + va.y * g.y;
    a1 += vb.x * g.x + vb.y * g.y;
  }
  if (lane < 2) {
    const float2 g = gr[448 + lane];
    const float2 va = wr0[448 + lane];
    const float2 vb = wr1[448 + lane];
    a0 += va.x * g.x + va.y * g.y;
    a1 += vb.x * g.x + vb.y * g.y;
  }
#pragma unroll
  for (int off = 32; off >= 1; off >>= 1) {
    a0 += __shfl_down(a0, off, 64);
    a1 += __shfl_down(a1, off, 64);
  }
  if (lane == 0) {
    out[b * CC + c0] = a0 + bias2[c0];
    out[b * CC + c0 + 1] = a1 + bias2[c0 + 1];
  }
}

// ---------------------------------------------------------------------------
extern "C" void kernel_launch(void* const* d_in, const int* in_sizes, int n_in,
                              void* d_out, int out_size, void* d_ws,
                              size_t ws_size, hipStream_t stream) {
  const int* x = (const int*)d_in[0];
  const float* embed = (const float*)d_in[1];
  const float* conv_w = (const float*)d_in[2];
  const float* conv_b = (const float*)d_in[3];
  const float* fc3w = (const float*)d_in[4];
  const float* fc3b = (const float*)d_in[5];
  const float* fc4w = (const float*)d_in[6];
  const float* fc4b = (const float*)d_in[7];
  const float* fc5w = (const float*)d_in[8];
  const float* fc5b = (const float*)d_in[9];
  const float* fcw = (const float*)d_in[10];
  const float* fcb = (const float*)d_in[11];

  float* Gpart = (float*)d_ws;
  float* Gred = (float*)d_ws + OFF_GRED;
  float* W2 = (float*)d_ws + OFF_W2;
  float* bias2 = (float*)d_ws + OFF_BIAS2;

  k_gather<<<dim3(1434), dim3(320), 0, stream>>>(
      x, embed, conv_w, conv_b, fc3w, fc3b, fc4w, fc4b, fc5w, fc5b, fcw, fcb,
      Gpart, W2, bias2);
  k_reduce<<<dim3(900), dim3(256), 0, stream>>>(Gpart, Gred);
  k_out<<<dim3(1024), dim3(256), 0, stream>>>(Gred, W2, bias2,
                                              (float*)d_out);
}